// Round 5
// baseline (415.703 us; speedup 1.0000x reference)
//
#include <hip/hip_runtime.h>
#include <stdint.h>

typedef uint32_t u32;
typedef uint16_t u16;

static constexpr int M_DIM = 8192;
static constexpr int N_DIM = 1024;
static constexpr int K_DIM = 4096;
static constexpr int BM = 128;
static constexpr int BN = 128;
static constexpr int BK = 32;
static constexpr int K_TILES = K_DIM / BK;       // 128
static constexpr int MB_TILES = M_DIM / 16;      // 512 16-row blocks
static constexpr int NB_TILES = N_DIM / 16;      // 64  16-col blocks

// fragment = 16 rows x 32 k of fp16, stored in exact MFMA lane order: 64 lanes x 16 B = 1 KiB
static constexpr size_t FRAG_U16 = 512;
static constexpr size_t HT_BYTES = (size_t)MB_TILES * K_TILES * FRAG_U16 * 2;  // 64 MiB
static constexpr size_t WT_BYTES = (size_t)NB_TILES * K_TILES * FRAG_U16 * 2;  // 8 MiB
static constexpr size_t WS_NEEDED = HT_BYTES + WT_BYTES;                       // 72 MiB

typedef __attribute__((ext_vector_type(8))) _Float16 half8;  // MFMA A/B frag (4 VGPRs)
typedef __attribute__((ext_vector_type(4))) float f32x4;     // MFMA C/D frag

__device__ __forceinline__ u32 pack2(float a, float b) {
  union { _Float16 h[2]; u32 u; } p;
  p.h[0] = (_Float16)a;   // v_cvt_f16_f32, RNE
  p.h[1] = (_Float16)b;
  return p.u;
}

// GELU via Abramowitz-Stegun 7.1.26 erf (|err| <= 1.5e-7) + dropout keep-mask * 1/(1-0.1).
__device__ __forceinline__ float gelu_drop(float x, u32 keep) {
  float ax = fabsf(x);
  float z  = ax * 0.70710678f;
  float t  = __builtin_amdgcn_rcpf(fmaf(0.3275911f, z, 1.0f));
  float poly = fmaf(fmaf(fmaf(fmaf(1.061405429f, t, -1.453152027f),
                              t, 1.421413741f),
                         t, -0.284496736f),
                    t, 0.254829592f) * t;
  float e   = exp2f(z * z * -1.44269504f);    // exp(-z^2)
  float erf = fmaf(-poly, e, 1.0f);           // erf(|x|/sqrt(2)) in [0,1)
  float g   = 0.5f * x * (1.0f + copysignf(erf, x));
  return keep ? g * 1.1111112f : 0.0f;
}

__device__ __forceinline__ void async_cp16(const void* g, void* l) {
  __builtin_amdgcn_global_load_lds((__attribute__((address_space(1))) u32*)g,
                                   (__attribute__((address_space(3))) u32*)l,
                                   16, 0, 0);
}

// ---------------- pass 1: fragment-major pack ----------------
// wave fi < H_WAVES: h-fragment (mb = fi>>7, kt = fi&127): lane l holds
//   h[mb*16 + (l&15)][kt*32 + (l>>4)*8 + j], j=0..7  -> Ht[fi*512 + l*8]
// wave fi >= H_WAVES: same for w -> Wt.
static constexpr int H_WAVES = MB_TILES * K_TILES;           // 65536
static constexpr int W_WAVES = NB_TILES * K_TILES;           // 8192
static constexpr int PACK_BLOCKS = (H_WAVES + W_WAVES) / 4;  // 18432

__global__ __launch_bounds__(256)
void pack_kernel(const float* __restrict__ X, const int* __restrict__ Mask,
                 const float* __restrict__ W, u16* __restrict__ Ht, u16* __restrict__ Wt) {
  const int l     = threadIdx.x & 63;
  const int fi    = blockIdx.x * 4 + (threadIdx.x >> 6);
  const int row16 = l & 15;
  const int kof   = (l >> 4) << 3;

  if (fi < H_WAVES) {
    const int mb = fi >> 7, kt = fi & 127;
    const float* xp = X    + (size_t)(mb * 16 + row16) * K_DIM + kt * 32 + kof;
    const int*   mp = Mask + (size_t)(mb * 16 + row16) * K_DIM + kt * 32 + kof;
    float4 x0 = *(const float4*)(xp + 0);
    float4 x1 = *(const float4*)(xp + 4);
    uint4  m0 = *(const uint4*)(mp + 0);
    uint4  m1 = *(const uint4*)(mp + 4);
    u32 o0 = pack2(gelu_drop(x0.x, m0.x), gelu_drop(x0.y, m0.y));
    u32 o1 = pack2(gelu_drop(x0.z, m0.z), gelu_drop(x0.w, m0.w));
    u32 o2 = pack2(gelu_drop(x1.x, m1.x), gelu_drop(x1.y, m1.y));
    u32 o3 = pack2(gelu_drop(x1.z, m1.z), gelu_drop(x1.w, m1.w));
    *(uint4*)(Ht + (size_t)fi * FRAG_U16 + l * 8) = make_uint4(o0, o1, o2, o3);
  } else {
    const int fj = fi - H_WAVES;
    const int nb = fj >> 7, kt = fj & 127;
    const float* wp = W + (size_t)(nb * 16 + row16) * K_DIM + kt * 32 + kof;
    float4 w0 = *(const float4*)(wp + 0);
    float4 w1 = *(const float4*)(wp + 4);
    u32 o0 = pack2(w0.x, w0.y);
    u32 o1 = pack2(w0.z, w0.w);
    u32 o2 = pack2(w1.x, w1.y);
    u32 o3 = pack2(w1.z, w1.w);
    *(uint4*)(Wt + (size_t)fj * FRAG_U16 + l * 8) = make_uint4(o0, o1, o2, o3);
  }
}

// ---------------- pass 2: fragment-layout GEMM, double-buffered, 1 barrier/kt ----------------
__global__ __launch_bounds__(256, 2)
void gemm_kernel(const u16* __restrict__ Ht, const u16* __restrict__ Wt,
                 const float* __restrict__ Bias, float* __restrict__ Out) {
  // each buffer: 8 fragments x 1 KiB, filled by async_cp16 in slot order (dst = base + tid*16)
  __shared__ __attribute__((aligned(16))) u16 Abuf[2][BM * BK];  // 2 x 8 KiB
  __shared__ __attribute__((aligned(16))) u16 Bbuf[2][BN * BK];  // 2 x 8 KiB

  const int tid  = threadIdx.x;
  const int lane = tid & 63;
  const int wv   = tid >> 6;
  const int wr   = wv >> 1;   // wave row 0..1
  const int wc   = wv & 1;    // wave col 0..1

  // m-fast order: same-m blocks (all 8 bn) share an XCD (%8) -> h re-reads are L2-hit.
  const int bm = blockIdx.x & 63;
  const int bn = blockIdx.x >> 6;
  const int m0 = bm * BM;
  const int n0 = bn * BN;

  // async staging sources: slot s = frag (s>>6) of this tile, lane (s&63); s in {tid, tid+256}
  const char* aG = (const char*)Ht;
  const char* bG = (const char*)Wt;
  const size_t aOff0 = ((size_t)(bm * 8 +     (tid >> 6)) * K_TILES) * 1024 + (size_t)lane * 16;
  const size_t aOff1 = ((size_t)(bm * 8 + 4 + (tid >> 6)) * K_TILES) * 1024 + (size_t)lane * 16;
  const size_t bOff0 = ((size_t)(bn * 8 +     (tid >> 6)) * K_TILES) * 1024 + (size_t)lane * 16;
  const size_t bOff1 = ((size_t)(bn * 8 + 4 + (tid >> 6)) * K_TILES) * 1024 + (size_t)lane * 16;

  f32x4 acc[4][4];
#pragma unroll
  for (int i = 0; i < 4; ++i)
#pragma unroll
    for (int j = 0; j < 4; ++j)
      acc[i][j] = (f32x4){0.f, 0.f, 0.f, 0.f};

  // stage k-tile 0 into buffer 0
  {
    async_cp16(aG + aOff0, (char*)Abuf[0] + tid * 16);
    async_cp16(aG + aOff1, (char*)Abuf[0] + (tid + 256) * 16);
    async_cp16(bG + bOff0, (char*)Bbuf[0] + tid * 16);
    async_cp16(bG + bOff1, (char*)Bbuf[0] + (tid + 256) * 16);
  }
  __syncthreads();

#pragma unroll 1
  for (int kt = 0; kt < K_TILES; ++kt) {
    const int cur = kt & 1;
    // prefetch next k-tile into the other buffer; it has the whole MFMA phase to land
    if (kt + 1 < K_TILES) {
      const size_t ko = (size_t)(kt + 1) * 1024;
      char* ad = (char*)Abuf[cur ^ 1];
      char* bd = (char*)Bbuf[cur ^ 1];
      async_cp16(aG + aOff0 + ko, ad + tid * 16);
      async_cp16(aG + aOff1 + ko, ad + (tid + 256) * 16);
      async_cp16(bG + bOff0 + ko, bd + tid * 16);
      async_cp16(bG + bOff1 + ko, bd + (tid + 256) * 16);
    }

    // contiguous, conflict-free LDS fragment reads (1 KiB per wave per read)
    half8 ar[4], br[4];
#pragma unroll
    for (int i = 0; i < 4; ++i)
      ar[i] = *(const half8*)((const char*)Abuf[cur] + ((wr * 4 + i) * 64 + lane) * 16);
#pragma unroll
    for (int j = 0; j < 4; ++j)
      br[j] = *(const half8*)((const char*)Bbuf[cur] + ((wc * 4 + j) * 64 + lane) * 16);

#pragma unroll
    for (int i = 0; i < 4; ++i)
#pragma unroll
      for (int j = 0; j < 4; ++j)
        acc[i][j] = __builtin_amdgcn_mfma_f32_16x16x32_f16(ar[i], br[j], acc[i][j], 0, 0, 0);

    __syncthreads();  // single barrier: drains next-tile asyncs + guards buffer reuse
  }

  // epilogue: C/D layout col = lane&15, row = (lane>>4)*4 + reg  [verified R3/R4]
  const int fr = lane & 15;
  const int rq = (lane >> 4) << 2;
  float bv[4];
#pragma unroll
  for (int j = 0; j < 4; ++j)
    bv[j] = Bias[n0 + wc * 64 + j * 16 + fr];

#pragma unroll
  for (int i = 0; i < 4; ++i) {
    const int row0 = m0 + wr * 64 + i * 16 + rq;
#pragma unroll
    for (int j = 0; j < 4; ++j) {
      const int col = n0 + wc * 64 + j * 16 + fr;
#pragma unroll
      for (int r = 0; r < 4; ++r) {
        Out[(size_t)(row0 + r) * N_DIM + col] = acc[i][j][r] + bv[j];
      }
    }
  }
}

// ---------------- fallback: verified R3 fused kernel (only if ws too small) ----------------
static constexpr int A_STRIDE = 40;

__global__ __launch_bounds__(256, 2)
void fused_fallback_kernel(const float* __restrict__ X, const float* __restrict__ W,
                           const float* __restrict__ Bias, const int* __restrict__ Mask,
                           float* __restrict__ Out) {
  __shared__ __attribute__((aligned(16))) _Float16 As[BM * A_STRIDE];
  __shared__ __attribute__((aligned(16))) _Float16 Bs[BN * BK];

  const int tid  = threadIdx.x;
  const int lane = tid & 63;
  const int wv   = tid >> 6;
  const int wr   = wv >> 1;
  const int wc   = wv & 1;
  const int bm = blockIdx.x & 63;
  const int bn = blockIdx.x >> 6;
  const int m0 = bm * BM;
  const int n0 = bn * BN;

  const int a_m = tid >> 1;
  const int a_k = (tid & 1) << 4;
  const float* xptr = X    + (size_t)(m0 + a_m) * K_DIM + a_k;
  const int*   mptr = Mask + (size_t)(m0 + a_m) * K_DIM + a_k;
  _Float16* a_lds = &As[a_m * A_STRIDE + a_k];

  const int i0 = tid, i1 = tid + 256;
  const float* wp0 = W + (size_t)(n0 + (i0 >> 2)) * K_DIM + ((i0 & 3) << 3);
  const float* wp1 = W + (size_t)(n0 + (i1 >> 2)) * K_DIM + ((i1 & 3) << 3);
  _Float16* bl0 = &Bs[i0 * 8];
  _Float16* bl1 = &Bs[i1 * 8];

  f32x4 acc[4][4];
#pragma unroll
  for (int i = 0; i < 4; ++i)
#pragma unroll
    for (int j = 0; j < 4; ++j)
      acc[i][j] = (f32x4){0.f, 0.f, 0.f, 0.f};

  float4 xf0 = *(const float4*)(xptr +  0);
  float4 xf1 = *(const float4*)(xptr +  4);
  float4 xf2 = *(const float4*)(xptr +  8);
  float4 xf3 = *(const float4*)(xptr + 12);
  uint4  mr0 = *(const uint4*)(mptr +  0);
  uint4  mr1 = *(const uint4*)(mptr +  4);
  uint4  mr2 = *(const uint4*)(mptr +  8);
  uint4  mr3 = *(const uint4*)(mptr + 12);
  float4 wf0 = *(const float4*)(wp0 + 0);
  float4 wf1 = *(const float4*)(wp0 + 4);
  float4 wf2 = *(const float4*)(wp1 + 0);
  float4 wf3 = *(const float4*)(wp1 + 4);

#pragma unroll 1
  for (int kt = 0; kt < K_TILES; ++kt) {
    {
      float xs[16] = {xf0.x, xf0.y, xf0.z, xf0.w, xf1.x, xf1.y, xf1.z, xf1.w,
                      xf2.x, xf2.y, xf2.z, xf2.w, xf3.x, xf3.y, xf3.z, xf3.w};
      u32 mk[16]   = {mr0.x, mr0.y, mr0.z, mr0.w, mr1.x, mr1.y, mr1.z, mr1.w,
                      mr2.x, mr2.y, mr2.z, mr2.w, mr3.x, mr3.y, mr3.z, mr3.w};
      u32 ow[8];
#pragma unroll
      for (int e = 0; e < 8; ++e)
        ow[e] = pack2(gelu_drop(xs[2 * e], mk[2 * e]), gelu_drop(xs[2 * e + 1], mk[2 * e + 1]));
      ((uint4*)a_lds)[0] = make_uint4(ow[0], ow[1], ow[2], ow[3]);
      ((uint4*)a_lds)[1] = make_uint4(ow[4], ow[5], ow[6], ow[7]);
    }
    {
      *(uint4*)bl0 = make_uint4(pack2(wf0.x, wf0.y), pack2(wf0.z, wf0.w),
                                pack2(wf1.x, wf1.y), pack2(wf1.z, wf1.w));
      *(uint4*)bl1 = make_uint4(pack2(wf2.x, wf2.y), pack2(wf2.z, wf2.w),
                                pack2(wf3.x, wf3.y), pack2(wf3.z, wf3.w));
    }
    __syncthreads();

    if (kt + 1 < K_TILES) {
      xptr += BK; mptr += BK; wp0 += BK; wp1 += BK;
      xf0 = *(const float4*)(xptr +  0);
      xf1 = *(const float4*)(xptr +  4);
      xf2 = *(const float4*)(xptr +  8);
      xf3 = *(const float4*)(xptr + 12);
      mr0 = *(const uint4*)(mptr +  0);
      mr1 = *(const uint4*)(mptr +  4);
      mr2 = *(const uint4*)(mptr +  8);
      mr3 = *(const uint4*)(mptr + 12);
      wf0 = *(const float4*)(wp0 + 0);
      wf1 = *(const float4*)(wp0 + 4);
      wf2 = *(const float4*)(wp1 + 0);
      wf3 = *(const float4*)(wp1 + 4);
    }

    {
      const int fr2 = lane & 15;
      const int fk2 = (lane >> 4) << 3;
      half8 ar[4], br[4];
#pragma unroll
      for (int i = 0; i < 4; ++i)
        ar[i] = *(const half8*)&As[(wr * 64 + i * 16 + fr2) * A_STRIDE + fk2];
#pragma unroll
      for (int j = 0; j < 4; ++j)
        br[j] = *(const half8*)&Bs[(wc * 64 + j * 16 + fr2) * BK + fk2];
#pragma unroll
      for (int i = 0; i < 4; ++i)
#pragma unroll
        for (int j = 0; j < 4; ++j)
          acc[i][j] = __builtin_amdgcn_mfma_f32_16x16x32_f16(ar[i], br[j], acc[i][j], 0, 0, 0);
    }
    __syncthreads();
  }

  const int fr = lane & 15;
  const int rq = (lane >> 4) << 2;
  float bv[4];
#pragma unroll
  for (int j = 0; j < 4; ++j)
    bv[j] = Bias[n0 + wc * 64 + j * 16 + fr];
#pragma unroll
  for (int i = 0; i < 4; ++i) {
    const int row0 = m0 + wr * 64 + i * 16 + rq;
#pragma unroll
    for (int j = 0; j < 4; ++j) {
      const int col = n0 + wc * 64 + j * 16 + fr;
#pragma unroll
      for (int r = 0; r < 4; ++r)
        Out[(size_t)(row0 + r) * N_DIM + col] = acc[i][j][r] + bv[j];
    }
  }
}

extern "C" void kernel_launch(void* const* d_in, const int* in_sizes, int n_in,
                              void* d_out, int out_size, void* d_ws, size_t ws_size,
                              hipStream_t stream) {
  const float* X    = (const float*)d_in[0];   // x (8192x4096), fp16 canonicalized to f32
  const float* W    = (const float*)d_in[1];   // weight (1024x4096) f32, K-contiguous
  const float* Bias = (const float*)d_in[2];   // bias (1024) f32
  const int*   Mk   = (const int*)d_in[3];     // keep-mask int32 0/1
  float* Out = (float*)d_out;                  // y (8192x1024) f32

  if (ws_size >= WS_NEEDED) {
    u16* Ht = (u16*)d_ws;
    u16* Wt = (u16*)((char*)d_ws + HT_BYTES);
    pack_kernel<<<PACK_BLOCKS, 256, 0, stream>>>(X, Mk, W, Ht, Wt);
    gemm_kernel<<<(M_DIM / BM) * (N_DIM / BN), 256, 0, stream>>>(Ht, Wt, Bias, Out);
  } else {
    fused_fallback_kernel<<<(M_DIM / BM) * (N_DIM / BN), 256, 0, stream>>>(X, W, Bias, Mk, Out);
  }
}

// Round 6
// 397.279 us; speedup vs baseline: 1.0464x; 1.0464x over previous
//
#include <hip/hip_runtime.h>
#include <stdint.h>

typedef uint32_t u32;
typedef uint16_t u16;

static constexpr int M_DIM = 8192;
static constexpr int N_DIM = 1024;
static constexpr int K_DIM = 4096;

// gemm geometry
static constexpr int BM = 128;
static constexpr int BN = 256;
static constexpr int BK = 64;
static constexpr int KT64 = K_DIM / BK;          // 64 k-tiles
static constexpr int K_TILES32 = K_DIM / 32;     // 128 32-k fragments along K
static constexpr int MB_TILES = M_DIM / 16;      // 512
static constexpr int NB_TILES = N_DIM / 16;      // 64

// fragment = 16 rows x 32 k fp16 in exact MFMA lane order: 64 lanes x 16 B = 1 KiB
static constexpr size_t FRAG_U16 = 512;
static constexpr size_t HT_BYTES = (size_t)MB_TILES * K_TILES32 * FRAG_U16 * 2;  // 64 MiB
static constexpr size_t WT_BYTES = (size_t)NB_TILES * K_TILES32 * FRAG_U16 * 2;  // 8 MiB
static constexpr size_t WS_NEEDED = HT_BYTES + WT_BYTES;                         // 72 MiB

typedef __attribute__((ext_vector_type(8))) _Float16 half8;  // MFMA A/B frag (4 VGPRs)
typedef __attribute__((ext_vector_type(4))) float f32x4;     // MFMA C/D frag

union u4h8 { uint4 u; half8 h; };

__device__ __forceinline__ u32 pack2(float a, float b) {
  union { _Float16 h[2]; u32 u; } p;
  p.h[0] = (_Float16)a;   // v_cvt_f16_f32, RNE
  p.h[1] = (_Float16)b;
  return p.u;
}

// GELU via Abramowitz-Stegun 7.1.26 erf (|err| <= 1.5e-7) + dropout keep-mask * 1/(1-0.1).
__device__ __forceinline__ float gelu_drop(float x, u32 keep) {
  float ax = fabsf(x);
  float z  = ax * 0.70710678f;
  float t  = __builtin_amdgcn_rcpf(fmaf(0.3275911f, z, 1.0f));
  float poly = fmaf(fmaf(fmaf(fmaf(1.061405429f, t, -1.453152027f),
                              t, 1.421413741f),
                         t, -0.284496736f),
                    t, 0.254829592f) * t;
  float e   = exp2f(z * z * -1.44269504f);    // exp(-z^2)
  float erf = fmaf(-poly, e, 1.0f);           // erf(|x|/sqrt(2)) in [0,1)
  float g   = 0.5f * x * (1.0f + copysignf(erf, x));
  return keep ? g * 1.1111112f : 0.0f;
}

__device__ __forceinline__ void async_cp16(const void* g, void* l) {
  __builtin_amdgcn_global_load_lds((__attribute__((address_space(1))) u32*)g,
                                   (__attribute__((address_space(3))) u32*)l,
                                   16, 0, 0);
}

// ---------------- pass 1: fragment-major pack (verified R5) ----------------
static constexpr int H_WAVES = MB_TILES * K_TILES32;         // 65536
static constexpr int W_WAVES = NB_TILES * K_TILES32;         // 8192
static constexpr int PACK_BLOCKS = (H_WAVES + W_WAVES) / 4;  // 18432

__global__ __launch_bounds__(256)
void pack_kernel(const float* __restrict__ X, const int* __restrict__ Mask,
                 const float* __restrict__ W, u16* __restrict__ Ht, u16* __restrict__ Wt) {
  const int l     = threadIdx.x & 63;
  const int fi    = blockIdx.x * 4 + (threadIdx.x >> 6);
  const int row16 = l & 15;
  const int kof   = (l >> 4) << 3;

  if (fi < H_WAVES) {
    const int mb = fi >> 7, kt = fi & 127;
    const float* xp = X    + (size_t)(mb * 16 + row16) * K_DIM + kt * 32 + kof;
    const int*   mp = Mask + (size_t)(mb * 16 + row16) * K_DIM + kt * 32 + kof;
    float4 x0 = *(const float4*)(xp + 0);
    float4 x1 = *(const float4*)(xp + 4);
    uint4  m0 = *(const uint4*)(mp + 0);
    uint4  m1 = *(const uint4*)(mp + 4);
    u32 o0 = pack2(gelu_drop(x0.x, m0.x), gelu_drop(x0.y, m0.y));
    u32 o1 = pack2(gelu_drop(x0.z, m0.z), gelu_drop(x0.w, m0.w));
    u32 o2 = pack2(gelu_drop(x1.x, m1.x), gelu_drop(x1.y, m1.y));
    u32 o3 = pack2(gelu_drop(x1.z, m1.z), gelu_drop(x1.w, m1.w));
    *(uint4*)(Ht + (size_t)fi * FRAG_U16 + l * 8) = make_uint4(o0, o1, o2, o3);
  } else {
    const int fj = fi - H_WAVES;
    const int nb = fj >> 7, kt = fj & 127;
    const float* wp = W + (size_t)(nb * 16 + row16) * K_DIM + kt * 32 + kof;
    float4 w0 = *(const float4*)(wp + 0);
    float4 w1 = *(const float4*)(wp + 4);
    *(uint4*)(Wt + (size_t)fj * FRAG_U16 + l * 8) =
        make_uint4(pack2(w0.x, w0.y), pack2(w0.z, w0.w), pack2(w1.x, w1.y), pack2(w1.z, w1.w));
  }
}

// ---------------- pass 2: 128x256 blocks, B direct to VGPR, A via LDS dbuf ----------------
__global__ __launch_bounds__(512, 2)
void gemm_kernel(const u16* __restrict__ Ht, const u16* __restrict__ Wt,
                 const float* __restrict__ Bias, float* __restrict__ Out) {
  __shared__ __attribute__((aligned(16))) u16 Abuf[2][BM * BK];  // 2 x 16 KiB

  const int tid  = threadIdx.x;
  const int lane = tid & 63;
  const int wv   = tid >> 6;   // 0..7
  const int wr   = wv >> 2;    // m half 0..1
  const int wc   = wv & 3;     // n quarter 0..3

  // bm fast -> all 4 bn-blocks of a row-stripe share an XCD (%8): h re-reads are L2-hit.
  const int bm = blockIdx.x & 63;
  const int bn = blockIdx.x >> 6;
  const int m0 = bm * BM;
  const int n0 = bn * BN;

  // ---- A async staging: slots s = tid, tid+512; frag f2 = s>>6: mfrag=f2>>1, kk=f2&1 ----
  const char* aG = (const char*)Ht;
  const int f2_0 = tid >> 6;           // 0..7
  const int f2_1 = (tid + 512) >> 6;   // 8..15
  const size_t aBase0 = ((size_t)(bm * 8 + (f2_0 >> 1)) * K_TILES32 + (f2_0 & 1)) * 1024 + (size_t)lane * 16;
  const size_t aBase1 = ((size_t)(bm * 8 + (f2_1 >> 1)) * K_TILES32 + (f2_1 & 1)) * 1024 + (size_t)lane * 16;
  char* aDst0[2] = {(char*)Abuf[0] + tid * 16, (char*)Abuf[1] + tid * 16};
  char* aDst1[2] = {(char*)Abuf[0] + (tid + 512) * 16, (char*)Abuf[1] + (tid + 512) * 16};

  // ---- B direct-load pointers: q = j*2+kk, frag (bn*16 + wc*4 + j), 32-k slot kk ----
  const char* bp[8];
#pragma unroll
  for (int j = 0; j < 4; ++j)
#pragma unroll
    for (int kk = 0; kk < 2; ++kk)
      bp[j * 2 + kk] = (const char*)Wt +
          ((size_t)(bn * 16 + wc * 4 + j) * K_TILES32 + kk) * 1024 + (size_t)lane * 16;

  f32x4 acc[4][4];
#pragma unroll
  for (int i = 0; i < 4; ++i)
#pragma unroll
    for (int j = 0; j < 4; ++j)
      acc[i][j] = (f32x4){0.f, 0.f, 0.f, 0.f};

  // ---- prologue: stage A kt0 -> buf0, load B kt0 -> brE ----
  async_cp16(aG + aBase0, aDst0[0]);
  async_cp16(aG + aBase1, aDst1[0]);
  u4h8 brE[8], brO[8];
#pragma unroll
  for (int q = 0; q < 8; ++q) brE[q].u = *(const uint4*)(bp[q]);
  __syncthreads();

#pragma unroll 1
  for (int kt = 0; kt < KT64; kt += 2) {
    // ---- even: compute buf0/brE, prefetch kt+1 -> buf1/brO ----
    {
      const size_t ko = (size_t)(kt + 1) * 2048;
      async_cp16(aG + aBase0 + ko, aDst0[1]);
      async_cp16(aG + aBase1 + ko, aDst1[1]);
#pragma unroll
      for (int q = 0; q < 8; ++q) brO[q].u = *(const uint4*)(bp[q] + ko);

      half8 ar[2][4];
#pragma unroll
      for (int kk = 0; kk < 2; ++kk)
#pragma unroll
        for (int i = 0; i < 4; ++i)
          ar[kk][i] = *(const half8*)((const char*)Abuf[0] + (((wr * 4 + i) * 2 + kk) * 64 + lane) * 16);
#pragma unroll
      for (int kk = 0; kk < 2; ++kk)
#pragma unroll
        for (int i = 0; i < 4; ++i)
#pragma unroll
          for (int j = 0; j < 4; ++j)
            acc[i][j] = __builtin_amdgcn_mfma_f32_16x16x32_f16(ar[kk][i], brE[j * 2 + kk].h, acc[i][j], 0, 0, 0);
      __syncthreads();
    }
    // ---- odd: compute buf1/brO, prefetch kt+2 -> buf0/brE ----
    {
      if (kt + 2 < KT64) {
        const size_t ko = (size_t)(kt + 2) * 2048;
        async_cp16(aG + aBase0 + ko, aDst0[0]);
        async_cp16(aG + aBase1 + ko, aDst1[0]);
#pragma unroll
        for (int q = 0; q < 8; ++q) brE[q].u = *(const uint4*)(bp[q] + ko);
      }

      half8 ar[2][4];
#pragma unroll
      for (int kk = 0; kk < 2; ++kk)
#pragma unroll
        for (int i = 0; i < 4; ++i)
          ar[kk][i] = *(const half8*)((const char*)Abuf[1] + (((wr * 4 + i) * 2 + kk) * 64 + lane) * 16);
#pragma unroll
      for (int kk = 0; kk < 2; ++kk)
#pragma unroll
        for (int i = 0; i < 4; ++i)
#pragma unroll
          for (int j = 0; j < 4; ++j)
            acc[i][j] = __builtin_amdgcn_mfma_f32_16x16x32_f16(ar[kk][i], brO[j * 2 + kk].h, acc[i][j], 0, 0, 0);
      __syncthreads();
    }
  }

  // ---- epilogue: C/D layout col = lane&15, row = (lane>>4)*4 + reg  [verified R3-R5] ----
  const int fr = lane & 15;
  const int rq = (lane >> 4) << 2;
  float bv[4];
#pragma unroll
  for (int j = 0; j < 4; ++j)
    bv[j] = Bias[n0 + wc * 64 + j * 16 + fr];

#pragma unroll
  for (int i = 0; i < 4; ++i) {
    const int row0 = m0 + wr * 64 + i * 16 + rq;
#pragma unroll
    for (int j = 0; j < 4; ++j) {
      const int col = n0 + wc * 64 + j * 16 + fr;
#pragma unroll
      for (int r = 0; r < 4; ++r)
        Out[(size_t)(row0 + r) * N_DIM + col] = acc[i][j][r] + bv[j];
    }
  }
}

// ---------------- fallback: verified R3 fused kernel (only if ws too small) ----------------
static constexpr int A_STRIDE = 40;

__global__ __launch_bounds__(256, 2)
void fused_fallback_kernel(const float* __restrict__ X, const float* __restrict__ W,
                           const float* __restrict__ Bias, const int* __restrict__ Mask,
                           float* __restrict__ Out) {
  __shared__ __attribute__((aligned(16))) _Float16 As[128 * A_STRIDE];
  __shared__ __attribute__((aligned(16))) _Float16 Bs[128 * 32];

  const int tid  = threadIdx.x;
  const int lane = tid & 63;
  const int wv   = tid >> 6;
  const int wr   = wv >> 1;
  const int wc   = wv & 1;
  const int bm = blockIdx.x & 63;
  const int bn = blockIdx.x >> 6;
  const int m0 = bm * 128;
  const int n0 = bn * 128;

  const int a_m = tid >> 1;
  const int a_k = (tid & 1) << 4;
  const float* xptr = X    + (size_t)(m0 + a_m) * K_DIM + a_k;
  const int*   mptr = Mask + (size_t)(m0 + a_m) * K_DIM + a_k;
  _Float16* a_lds = &As[a_m * A_STRIDE + a_k];

  const int i0 = tid, i1 = tid + 256;
  const float* wp0 = W + (size_t)(n0 + (i0 >> 2)) * K_DIM + ((i0 & 3) << 3);
  const float* wp1 = W + (size_t)(n0 + (i1 >> 2)) * K_DIM + ((i1 & 3) << 3);
  _Float16* bl0 = &Bs[i0 * 8];
  _Float16* bl1 = &Bs[i1 * 8];

  f32x4 acc[4][4];
#pragma unroll
  for (int i = 0; i < 4; ++i)
#pragma unroll
    for (int j = 0; j < 4; ++j)
      acc[i][j] = (f32x4){0.f, 0.f, 0.f, 0.f};

  float4 xf0 = *(const float4*)(xptr +  0);
  float4 xf1 = *(const float4*)(xptr +  4);
  float4 xf2 = *(const float4*)(xptr +  8);
  float4 xf3 = *(const float4*)(xptr + 12);
  uint4  mr0 = *(const uint4*)(mptr +  0);
  uint4  mr1 = *(const uint4*)(mptr +  4);
  uint4  mr2 = *(const uint4*)(mptr +  8);
  uint4  mr3 = *(const uint4*)(mptr + 12);
  float4 wf0 = *(const float4*)(wp0 + 0);
  float4 wf1 = *(const float4*)(wp0 + 4);
  float4 wf2 = *(const float4*)(wp1 + 0);
  float4 wf3 = *(const float4*)(wp1 + 4);

#pragma unroll 1
  for (int kt = 0; kt < 128; ++kt) {
    {
      float xs[16] = {xf0.x, xf0.y, xf0.z, xf0.w, xf1.x, xf1.y, xf1.z, xf1.w,
                      xf2.x, xf2.y, xf2.z, xf2.w, xf3.x, xf3.y, xf3.z, xf3.w};
      u32 mk[16]   = {mr0.x, mr0.y, mr0.z, mr0.w, mr1.x, mr1.y, mr1.z, mr1.w,
                      mr2.x, mr2.y, mr2.z, mr2.w, mr3.x, mr3.y, mr3.z, mr3.w};
      u32 ow[8];
#pragma unroll
      for (int e = 0; e < 8; ++e)
        ow[e] = pack2(gelu_drop(xs[2 * e], mk[2 * e]), gelu_drop(xs[2 * e + 1], mk[2 * e + 1]));
      ((uint4*)a_lds)[0] = make_uint4(ow[0], ow[1], ow[2], ow[3]);
      ((uint4*)a_lds)[1] = make_uint4(ow[4], ow[5], ow[6], ow[7]);
    }
    {
      *(uint4*)bl0 = make_uint4(pack2(wf0.x, wf0.y), pack2(wf0.z, wf0.w),
                                pack2(wf1.x, wf1.y), pack2(wf1.z, wf1.w));
      *(uint4*)bl1 = make_uint4(pack2(wf2.x, wf2.y), pack2(wf2.z, wf2.w),
                                pack2(wf3.x, wf3.y), pack2(wf3.z, wf3.w));
    }
    __syncthreads();

    if (kt + 1 < 128) {
      xptr += 32; mptr += 32; wp0 += 32; wp1 += 32;
      xf0 = *(const float4*)(xptr +  0);
      xf1 = *(const float4*)(xptr +  4);
      xf2 = *(const float4*)(xptr +  8);
      xf3 = *(const float4*)(xptr + 12);
      mr0 = *(const uint4*)(mptr +  0);
      mr1 = *(const uint4*)(mptr +  4);
      mr2 = *(const uint4*)(mptr +  8);
      mr3 = *(const uint4*)(mptr + 12);
      wf0 = *(const float4*)(wp0 + 0);
      wf1 = *(const float4*)(wp0 + 4);
      wf2 = *(const float4*)(wp1 + 0);
      wf3 = *(const float4*)(wp1 + 4);
    }

    {
      const int fr2 = lane & 15;
      const int fk2 = (lane >> 4) << 3;
      half8 ar[4], br[4];
#pragma unroll
      for (int i = 0; i < 4; ++i)
        ar[i] = *(const half8*)&As[(wr * 64 + i * 16 + fr2) * A_STRIDE + fk2];
#pragma unroll
      for (int j = 0; j < 4; ++j)
        br[j] = *(const half8*)&Bs[(wc * 64 + j * 16 + fr2) * 32 + fk2];
#pragma unroll
      for (int i = 0; i < 4; ++i)
#pragma unroll
        for (int j = 0; j < 4; ++j)
          acc[i][j] = __builtin_amdgcn_mfma_f32_16x16x32_f16(ar[i], br[j], acc[i][j], 0, 0, 0);
    }
    __syncthreads();
  }

  const int fr = lane & 15;
  const int rq = (lane >> 4) << 2;
  float bv[4];
#pragma unroll
  for (int j = 0; j < 4; ++j)
    bv[j] = Bias[n0 + wc * 64 + j * 16 + fr];
#pragma unroll
  for (int i = 0; i < 4; ++i) {
    const int row0 = m0 + wr * 64 + i * 16 + rq;
#pragma unroll
    for (int j = 0; j < 4; ++j) {
      const int col = n0 + wc * 64 + j * 16 + fr;
#pragma unroll
      for (int r = 0; r < 4; ++r)
        Out[(size_t)(row0 + r) * N_DIM + col] = acc[i][j][r] + bv[j];
    }
  }
}

extern "C" void kernel_launch(void* const* d_in, const int* in_sizes, int n_in,
                              void* d_out, int out_size, void* d_ws, size_t ws_size,
                              hipStream_t stream) {
  const float* X    = (const float*)d_in[0];   // x (8192x4096), fp16 canonicalized to f32
  const float* W    = (const float*)d_in[1];   // weight (1024x4096) f32, K-contiguous
  const float* Bias = (const float*)d_in[2];   // bias (1024) f32
  const int*   Mk   = (const int*)d_in[3];     // keep-mask int32 0/1
  float* Out = (float*)d_out;                  // y (8192x1024) f32

  if (ws_size >= WS_NEEDED) {
    u16* Ht = (u16*)d_ws;
    u16* Wt = (u16*)((char*)d_ws + HT_BYTES);
    pack_kernel<<<PACK_BLOCKS, 256, 0, stream>>>(X, Mk, W, Ht, Wt);
    gemm_kernel<<<(M_DIM / BM) * (N_DIM / BN), 512, 0, stream>>>(Ht, Wt, Bias, Out);  // 256 blocks
  } else {
    fused_fallback_kernel<<<64 * 8, 256, 0, stream>>>(X, W, Bias, Mk, Out);
  }
}

// Round 7
// 392.142 us; speedup vs baseline: 1.0601x; 1.0131x over previous
//
#include <hip/hip_runtime.h>
#include <stdint.h>

typedef uint32_t u32;
typedef uint16_t u16;

static constexpr int M_DIM = 8192;
static constexpr int N_DIM = 1024;
static constexpr int K_DIM = 4096;

// gemm geometry: 256x128 tile, BK=64, 1 block/CU, both operands through LDS
static constexpr int BM = 256;
static constexpr int BN = 128;
static constexpr int BK = 64;
static constexpr int KT64 = K_DIM / BK;          // 64 k-tiles
static constexpr int K_TILES32 = K_DIM / 32;     // 128 32-k fragments along K
static constexpr int MB_TILES = M_DIM / 16;      // 512
static constexpr int NB_TILES = N_DIM / 16;      // 64

// fragment = 16 rows x 32 k fp16 in exact MFMA lane order: 64 lanes x 16 B = 1 KiB
static constexpr size_t FRAG_U16 = 512;
static constexpr size_t HT_BYTES = (size_t)MB_TILES * K_TILES32 * FRAG_U16 * 2;  // 64 MiB
static constexpr size_t WT_BYTES = (size_t)NB_TILES * K_TILES32 * FRAG_U16 * 2;  // 8 MiB
static constexpr size_t WS_NEEDED = HT_BYTES + WT_BYTES;                         // 72 MiB

typedef __attribute__((ext_vector_type(8))) _Float16 half8;  // MFMA A/B frag (4 VGPRs)
typedef __attribute__((ext_vector_type(4))) float f32x4;     // MFMA C/D frag

__device__ __forceinline__ u32 pack2(float a, float b) {
  union { _Float16 h[2]; u32 u; } p;
  p.h[0] = (_Float16)a;   // v_cvt_f16_f32, RNE
  p.h[1] = (_Float16)b;
  return p.u;
}

// GELU via Abramowitz-Stegun 7.1.26 erf (|err| <= 1.5e-7) + dropout keep-mask * 1/(1-0.1).
__device__ __forceinline__ float gelu_drop(float x, u32 keep) {
  float ax = fabsf(x);
  float z  = ax * 0.70710678f;
  float t  = __builtin_amdgcn_rcpf(fmaf(0.3275911f, z, 1.0f));
  float poly = fmaf(fmaf(fmaf(fmaf(1.061405429f, t, -1.453152027f),
                              t, 1.421413741f),
                         t, -0.284496736f),
                    t, 0.254829592f) * t;
  float e   = exp2f(z * z * -1.44269504f);    // exp(-z^2)
  float erf = fmaf(-poly, e, 1.0f);           // erf(|x|/sqrt(2)) in [0,1)
  float g   = 0.5f * x * (1.0f + copysignf(erf, x));
  return keep ? g * 1.1111112f : 0.0f;
}

__device__ __forceinline__ void async_cp16(const void* g, void* l) {
  __builtin_amdgcn_global_load_lds((__attribute__((address_space(1))) u32*)g,
                                   (__attribute__((address_space(3))) u32*)l,
                                   16, 0, 0);
}

// ---------------- pass 1: fragment-major pack (verified R5/R6, unchanged) ----------------
static constexpr int H_WAVES = MB_TILES * K_TILES32;         // 65536
static constexpr int W_WAVES = NB_TILES * K_TILES32;         // 8192
static constexpr int PACK_BLOCKS = (H_WAVES + W_WAVES) / 4;  // 18432

__global__ __launch_bounds__(256)
void pack_kernel(const float* __restrict__ X, const int* __restrict__ Mask,
                 const float* __restrict__ W, u16* __restrict__ Ht, u16* __restrict__ Wt) {
  const int l     = threadIdx.x & 63;
  const int fi    = blockIdx.x * 4 + (threadIdx.x >> 6);
  const int row16 = l & 15;
  const int kof   = (l >> 4) << 3;

  if (fi < H_WAVES) {
    const int mb = fi >> 7, kt = fi & 127;
    const float* xp = X    + (size_t)(mb * 16 + row16) * K_DIM + kt * 32 + kof;
    const int*   mp = Mask + (size_t)(mb * 16 + row16) * K_DIM + kt * 32 + kof;
    float4 x0 = *(const float4*)(xp + 0);
    float4 x1 = *(const float4*)(xp + 4);
    uint4  m0 = *(const uint4*)(mp + 0);
    uint4  m1 = *(const uint4*)(mp + 4);
    u32 o0 = pack2(gelu_drop(x0.x, m0.x), gelu_drop(x0.y, m0.y));
    u32 o1 = pack2(gelu_drop(x0.z, m0.z), gelu_drop(x0.w, m0.w));
    u32 o2 = pack2(gelu_drop(x1.x, m1.x), gelu_drop(x1.y, m1.y));
    u32 o3 = pack2(gelu_drop(x1.z, m1.z), gelu_drop(x1.w, m1.w));
    *(uint4*)(Ht + (size_t)fi * FRAG_U16 + l * 8) = make_uint4(o0, o1, o2, o3);
  } else {
    const int fj = fi - H_WAVES;
    const int nb = fj >> 7, kt = fj & 127;
    const float* wp = W + (size_t)(nb * 16 + row16) * K_DIM + kt * 32 + kof;
    float4 w0 = *(const float4*)(wp + 0);
    float4 w1 = *(const float4*)(wp + 4);
    *(uint4*)(Wt + (size_t)fj * FRAG_U16 + l * 8) =
        make_uint4(pack2(w0.x, w0.y), pack2(w0.z, w0.w), pack2(w1.x, w1.y), pack2(w1.z, w1.w));
  }
}

// ---------------- pass 2: 256x128 tile, A+B LDS dbuf, 1 barrier per 64-k tile ----------------
__global__ __launch_bounds__(512, 1)
void gemm_kernel(const u16* __restrict__ Ht, const u16* __restrict__ Wt,
                 const float* __restrict__ Bias, float* __restrict__ Out) {
  __shared__ __attribute__((aligned(16))) u16 Abuf[2][BM * BK];  // 2 x 32 KiB
  __shared__ __attribute__((aligned(16))) u16 Bbuf[2][BN * BK];  // 2 x 16 KiB

  const int tid  = threadIdx.x;
  const int lane = tid & 63;
  const int wv   = tid >> 6;   // 0..7
  const int wr   = wv >> 1;    // m quarter 0..3 (64 rows each)
  const int wc   = wv & 1;     // n half 0..1 (64 cols each)

  // bm fast -> the 8 bn-blocks sharing a row-stripe land on one XCD (%8): A is L2-shared x8.
  const int bm = blockIdx.x & 31;
  const int bn = blockIdx.x >> 5;
  const int m0 = bm * BM;
  const int n0 = bn * BN;

  // ---- staging source offsets (frag-major ws layout) ----
  // A: 4 slots/thread: s = tid + 512*p, frag f = s>>6 (0..31): mf = f>>1, kk = f&1
  // B: 2 slots/thread: s = tid + 512*p, frag f = s>>6 (0..15): nf = f>>1, kk = f&1
  const char* aG = (const char*)Ht;
  const char* bG = (const char*)Wt;
  size_t aOff[4], bOff[2];
#pragma unroll
  for (int p = 0; p < 4; ++p) {
    const int s = tid + 512 * p, f = s >> 6;
    aOff[p] = ((size_t)(bm * 16 + (f >> 1)) * K_TILES32 + (f & 1)) * 1024 + (size_t)(s & 63) * 16;
  }
#pragma unroll
  for (int p = 0; p < 2; ++p) {
    const int s = tid + 512 * p, f = s >> 6;
    bOff[p] = ((size_t)(bn * 8 + (f >> 1)) * K_TILES32 + (f & 1)) * 1024 + (size_t)(s & 63) * 16;
  }

  auto stage = [&](int kt, int buf) {
    const size_t ko = (size_t)kt * 2048;   // advance 2 k-frags (2 KiB) per 64-k tile
    char* ad = (char*)Abuf[buf];
    char* bd = (char*)Bbuf[buf];
#pragma unroll
    for (int p = 0; p < 4; ++p)
      async_cp16(aG + aOff[p] + ko, ad + (tid + 512 * p) * 16);
#pragma unroll
    for (int p = 0; p < 2; ++p)
      async_cp16(bG + bOff[p] + ko, bd + (tid + 512 * p) * 16);
  };

  f32x4 acc[4][4];
#pragma unroll
  for (int i = 0; i < 4; ++i)
#pragma unroll
    for (int j = 0; j < 4; ++j)
      acc[i][j] = (f32x4){0.f, 0.f, 0.f, 0.f};

  auto compute = [&](int buf) {
    const char* ab = (const char*)Abuf[buf];
    const char* bb = (const char*)Bbuf[buf];
#pragma unroll
    for (int kk = 0; kk < 2; ++kk) {
      half8 ar[4], br[4];
#pragma unroll
      for (int i = 0; i < 4; ++i)
        ar[i] = *(const half8*)(ab + (((wr * 4 + i) * 2 + kk) * 64 + lane) * 16);
#pragma unroll
      for (int j = 0; j < 4; ++j)
        br[j] = *(const half8*)(bb + (((wc * 4 + j) * 2 + kk) * 64 + lane) * 16);
#pragma unroll
      for (int i = 0; i < 4; ++i)
#pragma unroll
        for (int j = 0; j < 4; ++j)
          acc[i][j] = __builtin_amdgcn_mfma_f32_16x16x32_f16(ar[i], br[j], acc[i][j], 0, 0, 0);
    }
  };

  // prologue: stage kt0 -> buf0
  stage(0, 0);
  __syncthreads();

#pragma unroll 1
  for (int kt = 0; kt < KT64; kt += 2) {
    // even: prefetch kt+1 -> buf1, compute buf0
    if (kt + 1 < KT64) stage(kt + 1, 1);
    compute(0);
    __syncthreads();
    // odd: prefetch kt+2 -> buf0, compute buf1
    if (kt + 2 < KT64) stage(kt + 2, 0);
    compute(1);
    __syncthreads();
  }

  // ---- epilogue: C/D layout col = lane&15, row = (lane>>4)*4 + reg  [verified R3-R6] ----
  const int fr = lane & 15;
  const int rq = (lane >> 4) << 2;
  float bv[4];
#pragma unroll
  for (int j = 0; j < 4; ++j)
    bv[j] = Bias[n0 + wc * 64 + j * 16 + fr];

#pragma unroll
  for (int i = 0; i < 4; ++i) {
    const int row0 = m0 + wr * 64 + i * 16 + rq;
#pragma unroll
    for (int j = 0; j < 4; ++j) {
      const int col = n0 + wc * 64 + j * 16 + fr;
#pragma unroll
      for (int r = 0; r < 4; ++r)
        Out[(size_t)(row0 + r) * N_DIM + col] = acc[i][j][r] + bv[j];
    }
  }
}

// ---------------- fallback: verified R3 fused kernel (only if ws too small) ----------------
static constexpr int A_STRIDE = 40;

__global__ __launch_bounds__(256, 2)
void fused_fallback_kernel(const float* __restrict__ X, const float* __restrict__ W,
                           const float* __restrict__ Bias, const int* __restrict__ Mask,
                           float* __restrict__ Out) {
  __shared__ __attribute__((aligned(16))) _Float16 As[128 * A_STRIDE];
  __shared__ __attribute__((aligned(16))) _Float16 Bs[128 * 32];

  const int tid  = threadIdx.x;
  const int lane = tid & 63;
  const int wv   = tid >> 6;
  const int wr   = wv >> 1;
  const int wc   = wv & 1;
  const int bm = blockIdx.x & 63;
  const int bn = blockIdx.x >> 6;
  const int m0 = bm * 128;
  const int n0 = bn * 128;

  const int a_m = tid >> 1;
  const int a_k = (tid & 1) << 4;
  const float* xptr = X    + (size_t)(m0 + a_m) * K_DIM + a_k;
  const int*   mptr = Mask + (size_t)(m0 + a_m) * K_DIM + a_k;
  _Float16* a_lds = &As[a_m * A_STRIDE + a_k];

  const int i0 = tid, i1 = tid + 256;
  const float* wp0 = W + (size_t)(n0 + (i0 >> 2)) * K_DIM + ((i0 & 3) << 3);
  const float* wp1 = W + (size_t)(n0 + (i1 >> 2)) * K_DIM + ((i1 & 3) << 3);
  _Float16* bl0 = &Bs[i0 * 8];
  _Float16* bl1 = &Bs[i1 * 8];

  f32x4 acc[4][4];
#pragma unroll
  for (int i = 0; i < 4; ++i)
#pragma unroll
    for (int j = 0; j < 4; ++j)
      acc[i][j] = (f32x4){0.f, 0.f, 0.f, 0.f};

  float4 xf0 = *(const float4*)(xptr +  0);
  float4 xf1 = *(const float4*)(xptr +  4);
  float4 xf2 = *(const float4*)(xptr +  8);
  float4 xf3 = *(const float4*)(xptr + 12);
  uint4  mr0 = *(const uint4*)(mptr +  0);
  uint4  mr1 = *(const uint4*)(mptr +  4);
  uint4  mr2 = *(const uint4*)(mptr +  8);
  uint4  mr3 = *(const uint4*)(mptr + 12);
  float4 wf0 = *(const float4*)(wp0 + 0);
  float4 wf1 = *(const float4*)(wp0 + 4);
  float4 wf2 = *(const float4*)(wp1 + 0);
  float4 wf3 = *(const float4*)(wp1 + 4);

#pragma unroll 1
  for (int kt = 0; kt < 128; ++kt) {
    {
      float xs[16] = {xf0.x, xf0.y, xf0.z, xf0.w, xf1.x, xf1.y, xf1.z, xf1.w,
                      xf2.x, xf2.y, xf2.z, xf2.w, xf3.x, xf3.y, xf3.z, xf3.w};
      u32 mk[16]   = {mr0.x, mr0.y, mr0.z, mr0.w, mr1.x, mr1.y, mr1.z, mr1.w,
                      mr2.x, mr2.y, mr2.z, mr2.w, mr3.x, mr3.y, mr3.z, mr3.w};
      u32 ow[8];
#pragma unroll
      for (int e = 0; e < 8; ++e)
        ow[e] = pack2(gelu_drop(xs[2 * e], mk[2 * e]), gelu_drop(xs[2 * e + 1], mk[2 * e + 1]));
      ((uint4*)a_lds)[0] = make_uint4(ow[0], ow[1], ow[2], ow[3]);
      ((uint4*)a_lds)[1] = make_uint4(ow[4], ow[5], ow[6], ow[7]);
    }
    {
      *(uint4*)bl0 = make_uint4(pack2(wf0.x, wf0.y), pack2(wf0.z, wf0.w),
                                pack2(wf1.x, wf1.y), pack2(wf1.z, wf1.w));
      *(uint4*)bl1 = make_uint4(pack2(wf2.x, wf2.y), pack2(wf2.z, wf2.w),
                                pack2(wf3.x, wf3.y), pack2(wf3.z, wf3.w));
    }
    __syncthreads();

    if (kt + 1 < 128) {
      xptr += 32; mptr += 32; wp0 += 32; wp1 += 32;
      xf0 = *(const float4*)(xptr +  0);
      xf1 = *(const float4*)(xptr +  4);
      xf2 = *(const float4*)(xptr +  8);
      xf3 = *(const float4*)(xptr + 12);
      mr0 = *(const uint4*)(mptr +  0);
      mr1 = *(const uint4*)(mptr +  4);
      mr2 = *(const uint4*)(mptr +  8);
      mr3 = *(const uint4*)(mptr + 12);
      wf0 = *(const float4*)(wp0 + 0);
      wf1 = *(const float4*)(wp0 + 4);
      wf2 = *(const float4*)(wp1 + 0);
      wf3 = *(const float4*)(wp1 + 4);
    }

    {
      const int fr2 = lane & 15;
      const int fk2 = (lane >> 4) << 3;
      half8 ar[4], br[4];
#pragma unroll
      for (int i = 0; i < 4; ++i)
        ar[i] = *(const half8*)&As[(wr * 64 + i * 16 + fr2) * A_STRIDE + fk2];
#pragma unroll
      for (int j = 0; j < 4; ++j)
        br[j] = *(const half8*)&Bs[(wc * 64 + j * 16 + fr2) * 32 + fk2];
#pragma unroll
      for (int i = 0; i < 4; ++i)
#pragma unroll
        for (int j = 0; j < 4; ++j)
          acc[i][j] = __builtin_amdgcn_mfma_f32_16x16x32_f16(ar[i], br[j], acc[i][j], 0, 0, 0);
    }
    __syncthreads();
  }

  const int fr = lane & 15;
  const int rq = (lane >> 4) << 2;
  float bv[4];
#pragma unroll
  for (int j = 0; j < 4; ++j)
    bv[j] = Bias[n0 + wc * 64 + j * 16 + fr];
#pragma unroll
  for (int i = 0; i < 4; ++i) {
    const int row0 = m0 + wr * 64 + i * 16 + rq;
#pragma unroll
    for (int j = 0; j < 4; ++j) {
      const int col = n0 + wc * 64 + j * 16 + fr;
#pragma unroll
      for (int r = 0; r < 4; ++r)
        Out[(size_t)(row0 + r) * N_DIM + col] = acc[i][j][r] + bv[j];
    }
  }
}

extern "C" void kernel_launch(void* const* d_in, const int* in_sizes, int n_in,
                              void* d_out, int out_size, void* d_ws, size_t ws_size,
                              hipStream_t stream) {
  const float* X    = (const float*)d_in[0];   // x (8192x4096), fp16 canonicalized to f32
  const float* W    = (const float*)d_in[1];   // weight (1024x4096) f32, K-contiguous
  const float* Bias = (const float*)d_in[2];   // bias (1024) f32
  const int*   Mk   = (const int*)d_in[3];     // keep-mask int32 0/1
  float* Out = (float*)d_out;                  // y (8192x1024) f32

  if (ws_size >= WS_NEEDED) {
    u16* Ht = (u16*)d_ws;
    u16* Wt = (u16*)((char*)d_ws + HT_BYTES);
    pack_kernel<<<PACK_BLOCKS, 256, 0, stream>>>(X, Mk, W, Ht, Wt);
    gemm_kernel<<<(M_DIM / BM) * (N_DIM / BN), 512, 0, stream>>>(Ht, Wt, Bias, Out);  // 256 blocks
  } else {
    fused_fallback_kernel<<<64 * 8, 256, 0, stream>>>(X, W, Bias, Mk, Out);
  }
}